// Round 7
// baseline (51.174 us; speedup 1.0000x reference)
//
#include <hip/hip_runtime.h>

#define NBATCH 8
#define HH 256
#define WW 256
#define CC 64
#define HWPTS 65536   // HH*WW
#define NSTEPS_ 50

typedef float vf4 __attribute__((ext_vector_type(4)));

// ---------------------------------------------------------------------------
// Kernel 1: build per-(b,t) affine matrices A (2x3) from theta.
// Output layout (float2-packed, transposed for conflict-free LDS b64 reads):
//   Aout[b*192 + (w*32 + t)*2 + c],  w = 0..2 (x,y,1 coeff), c = 0:vx 1:vy
// ---------------------------------------------------------------------------
__global__ __launch_bounds__(256) void cpab_build_A(const float* __restrict__ theta,
                                                    float* __restrict__ Aout) {
  int tid = threadIdx.x;           // 0..255 == b*32 + t
  int b = tid >> 5, t = tid & 31;
  int cell = t >> 2, k = t & 3;
  int ci = cell & 1, cj = cell >> 1;
  int ll = cj * 3 + ci;
  int lr = ll + 1, ul = ll + 3, ur = ll + 4;
  int cen = 15 + cj * 2 + ci;
  int v0, v1, v2 = cen;
  if (k == 0)      { v0 = ll; v1 = lr; }
  else if (k == 1) { v0 = lr; v1 = ur; }
  else if (k == 2) { v0 = ur; v1 = ul; }
  else             { v0 = ul; v1 = ll; }

  int vs[3] = {v0, v1, v2};
  double xs[3], ys[3];
  float Vx[3], Vy[3];
  for (int q = 0; q < 3; ++q) {
    int v = vs[q];
    if (v < 15) { xs[q] = (double)(v % 3) * 0.5; ys[q] = (double)(v / 3) * 0.25; }
    else { int u = v - 15; xs[q] = ((double)(u & 1) + 0.5) * 0.5;
           ys[q] = ((double)(u >> 1) + 0.5) * 0.25; }
    int s = (v == 4) ? 0 : (v == 7) ? 1 : (v == 10) ? 2 : (v >= 15) ? (v - 12) : -1;
    if (s >= 0) { Vx[q] = theta[b * 22 + 2 * s]; Vy[q] = theta[b * 22 + 2 * s + 1]; }
    else        { Vx[q] = 0.f; Vy[q] = 0.f; }
  }
  double x0 = xs[0], x1 = xs[1], x2 = xs[2];
  double y0 = ys[0], y1 = ys[1], y2 = ys[2];
  double det = x0 * (y1 - y2) - x1 * (y0 - y2) + x2 * (y0 - y1);
  // P = [[x0,x1,x2],[y0,y1,y2],[1,1,1]];  inv = adj^T / det
  double inv[3][3] = {
      {y1 - y2, x2 - x1, x1 * y2 - x2 * y1},
      {y2 - y0, x0 - x2, x2 * y0 - x0 * y2},
      {y0 - y1, x1 - x0, x0 * y1 - x1 * y0}};
  for (int w = 0; w < 3; ++w) {
    float i0 = (float)(inv[0][w] / det);
    float i1 = (float)(inv[1][w] / det);
    float i2 = (float)(inv[2][w] / det);
    float ax = __fadd_rn(__fadd_rn(__fmul_rn(Vx[0], i0), __fmul_rn(Vx[1], i1)),
                         __fmul_rn(Vx[2], i2));
    float ay = __fadd_rn(__fadd_rn(__fmul_rn(Vy[0], i0), __fmul_rn(Vy[1], i1)),
                         __fmul_rn(Vy[2], i2));
    Aout[b * 192 + (w * 32 + t) * 2]     = ax;
    Aout[b * 192 + (w * 32 + t) * 2 + 1] = ay;
  }
}

// ---------------------------------------------------------------------------
// Kernel 2: 2048 blocks x 256 thr; block = one image row of one batch.
// WAVE-SELF-CONTAINED: each wave integrates its own 64 points into a
// wave-private LDS slice, then samples only those 64 points. No barrier
// between phases (intra-wave LDS RAW is in-order) -> waves drift freely,
// CU co-schedules VALU-phase waves with memory-phase waves.
// __launch_bounds__(256,8): VGPR<=64 -> 8 blocks/CU resident.
// Block swizzle: batch = bid&7 -> one batch per XCD (L2 locality).
// ---------------------------------------------------------------------------
__global__ __launch_bounds__(256, 8) void cpab_warp_sample(const float* __restrict__ xin,
                                                           const float* __restrict__ Ain,
                                                           float* __restrict__ out) {
  __shared__ float2 sA2[96];
  __shared__ int    sOff[256];
  __shared__ float4 sW[256];

  int tid = threadIdx.x;
  int bid = blockIdx.x;            // 2048 blocks
  int b = bid & 7;                 // batch == XCD
  int row = bid >> 3;              // image row 0..255
  int base_hw = row << 8;

  if (tid < 192) ((float*)sA2)[tid] = Ain[b * 192 + tid];
  __syncthreads();                 // everyone is at t=0 anyway; only sync point

  // ---- phase 1: integrate own point (w = tid, h = row) ----
  {
    // np.linspace(0,1,256): i * (1/255) with exact endpoint
    float px = (tid == 255) ? 1.0f : __fmul_rn((float)tid, 1.0f / 255.0f);
    float py = (row == 255) ? 1.0f : __fmul_rn((float)row, 1.0f / 255.0f);
#pragma unroll 1
    for (int s = 0; s < NSTEPS_; ++s) {
      float xc = fminf(fmaxf(px, 0.f), 1.f) * 2.0f;   // exact (*2)
      float yc = fminf(fmaxf(py, 0.f), 1.f) * 4.0f;   // exact (*4)
      float cxf = fminf(floorf(xc), 1.0f);
      float cyf = fminf(floorf(yc), 3.0f);
      float xr = xc - cxf, yr = yc - cyf;
      int tri = (yr <= xr) ? ((yr <= 1.0f - xr) ? 0 : 1)
                           : ((yr <= 1.0f - xr) ? 3 : 2);
      int cid = ((((int)cyf) << 1) + (int)cxf) * 4 + tri;
      float2 q0 = sA2[cid];        // {a00, a10}
      float2 q1 = sA2[32 + cid];   // {a01, a11}
      float2 q2 = sA2[64 + cid];   // {a02, a12}
      float vx = __fadd_rn(__fadd_rn(__fmul_rn(q0.x, px), __fmul_rn(q1.x, py)), q2.x);
      float vy = __fadd_rn(__fadd_rn(__fmul_rn(q0.y, px), __fmul_rn(q1.y, py)), q2.y);
      px = __fadd_rn(px, __fmul_rn(0.02f, vx));
      py = __fadd_rn(py, __fmul_rn(0.02f, vy));
    }
    float gx = __fmul_rn(fminf(fmaxf(px, 0.f), 1.f), 255.0f);
    float gy = __fmul_rn(fminf(fmaxf(py, 0.f), 1.f), 255.0f);
    int ix = min((int)gx, 254);   // gx >= 0 so (int) == floor
    int iy = min((int)gy, 254);
    float wx = __fadd_rn(gx, -(float)ix);
    float wy = __fadd_rn(gy, -(float)iy);
    sOff[tid] = (iy << 8) + ix;
    float4 w4;
    w4.x = (1.f - wx) * (1.f - wy);
    w4.y = wx * (1.f - wy);
    w4.z = (1.f - wx) * wy;
    w4.w = wx * wy;
    sW[tid] = w4;
  }
  // NO __syncthreads: each wave reads back only entries its own lanes wrote;
  // LDS ops of one wave execute in order, compiler keeps aliasing DS ordered.

  // ---- phase 2: sample this wave's 64 points ----
  int wv = tid >> 6;               // wave id 0..3
  int lp = (tid >> 4) & 3;         // point sub-index within group of 4
  int lc = tid & 15;               // channel chunk 0..15
  const float4* xb4 = (const float4*)(xin + (size_t)b * ((size_t)HWPTS * CC));
  float* ob = out + ((size_t)b * HWPTS + base_hw + (wv << 6)) * CC;

#pragma unroll
  for (int i = 0; i < 16; ++i) {
    int p = (wv << 6) + (i << 2) + lp;     // block-local point index
    int off = sOff[p];
    float4 W = sW[p];
    const float4* q = xb4 + ((size_t)off << 4) + lc;
    float4 L0 = q[0];
    float4 L1 = q[16];               // x0+1
    float4 L2 = q[16 * 256];         // y0+1
    float4 L3 = q[16 * 256 + 16];    // x0+1, y0+1
    vf4 o;
    o.x = L0.x * W.x + L1.x * W.y + L2.x * W.z + L3.x * W.w;
    o.y = L0.y * W.x + L1.y * W.y + L2.y * W.z + L3.y * W.w;
    o.z = L0.z * W.x + L1.z * W.y + L2.z * W.z + L3.z * W.w;
    o.w = L0.w * W.x + L1.w * W.y + L2.w * W.z + L3.w * W.w;
    __builtin_nontemporal_store(o, (vf4*)(ob + (size_t)((i << 2) + lp) * CC + (lc << 2)));
  }
}

extern "C" void kernel_launch(void* const* d_in, const int* in_sizes, int n_in,
                              void* d_out, int out_size, void* d_ws, size_t ws_size,
                              hipStream_t stream) {
  const float* x     = (const float*)d_in[0];   // (8,256,256,64) f32
  const float* theta = (const float*)d_in[1];   // (8,22) f32
  float* out  = (float*)d_out;                  // (8,256,256,64) f32
  float* Abuf = (float*)d_ws;                   // 8*192 floats = 6 KiB

  cpab_build_A<<<1, 256, 0, stream>>>(theta, Abuf);
  cpab_warp_sample<<<NBATCH * HWPTS / 256, 256, 0, stream>>>(x, Abuf, out);
}

// Round 8
// 50.485 us; speedup vs baseline: 1.0136x; 1.0136x over previous
//
#include <hip/hip_runtime.h>

#define NBATCH 8
#define HH 256
#define WW 256
#define CC 64
#define HWPTS 65536   // HH*WW
#define NSTEPS_ 50

typedef float vf4 __attribute__((ext_vector_type(4)));

// ---------------------------------------------------------------------------
// Kernel 1: build per-(b,t) affine matrices A (2x3) from theta.
// Output layout (float2-packed, transposed for conflict-free LDS b64 reads):
//   Aout[b*192 + (w*32 + t)*2 + c],  w = 0..2 (x,y,1 coeff), c = 0:vx 1:vy
// ---------------------------------------------------------------------------
__global__ __launch_bounds__(256) void cpab_build_A(const float* __restrict__ theta,
                                                    float* __restrict__ Aout) {
  int tid = threadIdx.x;           // 0..255 == b*32 + t
  int b = tid >> 5, t = tid & 31;
  int cell = t >> 2, k = t & 3;
  int ci = cell & 1, cj = cell >> 1;
  int ll = cj * 3 + ci;
  int lr = ll + 1, ul = ll + 3, ur = ll + 4;
  int cen = 15 + cj * 2 + ci;
  int v0, v1, v2 = cen;
  if (k == 0)      { v0 = ll; v1 = lr; }
  else if (k == 1) { v0 = lr; v1 = ur; }
  else if (k == 2) { v0 = ur; v1 = ul; }
  else             { v0 = ul; v1 = ll; }

  int vs[3] = {v0, v1, v2};
  double xs[3], ys[3];
  float Vx[3], Vy[3];
  for (int q = 0; q < 3; ++q) {
    int v = vs[q];
    if (v < 15) { xs[q] = (double)(v % 3) * 0.5; ys[q] = (double)(v / 3) * 0.25; }
    else { int u = v - 15; xs[q] = ((double)(u & 1) + 0.5) * 0.5;
           ys[q] = ((double)(u >> 1) + 0.5) * 0.25; }
    int s = (v == 4) ? 0 : (v == 7) ? 1 : (v == 10) ? 2 : (v >= 15) ? (v - 12) : -1;
    if (s >= 0) { Vx[q] = theta[b * 22 + 2 * s]; Vy[q] = theta[b * 22 + 2 * s + 1]; }
    else        { Vx[q] = 0.f; Vy[q] = 0.f; }
  }
  double x0 = xs[0], x1 = xs[1], x2 = xs[2];
  double y0 = ys[0], y1 = ys[1], y2 = ys[2];
  double det = x0 * (y1 - y2) - x1 * (y0 - y2) + x2 * (y0 - y1);
  // P = [[x0,x1,x2],[y0,y1,y2],[1,1,1]];  inv = adj^T / det
  double inv[3][3] = {
      {y1 - y2, x2 - x1, x1 * y2 - x2 * y1},
      {y2 - y0, x0 - x2, x2 * y0 - x0 * y2},
      {y0 - y1, x1 - x0, x0 * y1 - x1 * y0}};
  for (int w = 0; w < 3; ++w) {
    float i0 = (float)(inv[0][w] / det);
    float i1 = (float)(inv[1][w] / det);
    float i2 = (float)(inv[2][w] / det);
    float ax = __fadd_rn(__fadd_rn(__fmul_rn(Vx[0], i0), __fmul_rn(Vx[1], i1)),
                         __fmul_rn(Vx[2], i2));
    float ay = __fadd_rn(__fadd_rn(__fmul_rn(Vy[0], i0), __fmul_rn(Vy[1], i1)),
                         __fmul_rn(Vy[2], i2));
    Aout[b * 192 + (w * 32 + t) * 2]     = ax;
    Aout[b * 192 + (w * 32 + t) * 2 + 1] = ay;
  }
}

// ---------------------------------------------------------------------------
// Kernel 2: producer/consumer wave split. 2048 blocks x 256 thr,
// block = (batch b = bid&7 -> XCD, image row = bid>>3).
// Wave 3 integrates all 256 points in 4 chunks of 64, release-publishing
// sFlag after each chunk. Waves 0-2 acquire-spin then gather/blend/store
// their quarter of the 64 groups (4 pts x 16 chunks each); wave 3 samples
// its own quarter afterward (own data, no spin). Role diversity lets the
// CU co-schedule VALU (integrator) with memory (sampler) waves.
// ---------------------------------------------------------------------------
__global__ __launch_bounds__(256, 8) void cpab_pc(const float* __restrict__ xin,
                                                  const float* __restrict__ Ain,
                                                  float* __restrict__ out) {
  __shared__ float2 sA2[96];
  __shared__ int    sOff[256];
  __shared__ float4 sW[256];
  __shared__ int    sFlag;

  int tid = threadIdx.x;
  int bid = blockIdx.x;            // 2048 blocks
  int b = bid & 7;                 // batch == XCD
  int row = bid >> 3;              // image row 0..255

  if (tid == 0) sFlag = 0;
  if (tid < 192) ((float*)sA2)[tid] = Ain[b * 192 + tid];
  __syncthreads();

  int wv = tid >> 6;               // wave 0..3
  int lane = tid & 63;
  int lp = lane >> 4;              // point sub-index 0..3
  int lc = lane & 15;              // channel chunk 0..15
  const float4* xb4 = (const float4*)(xin + (size_t)b * ((size_t)HWPTS * CC));
  float* ob = out + ((size_t)b * HWPTS + ((size_t)row << 8)) * CC;
  float py_row = (row == 255) ? 1.0f : __fmul_rn((float)row, 1.0f / 255.0f);

  if (wv == 3) {
    // ---- producer: integrate 4 chunks of 64 points ----
#pragma unroll 1
    for (int c = 0; c < 4; ++c) {
      int p = (c << 6) + lane;     // 0..255 == w coordinate
      float px = (p == 255) ? 1.0f : __fmul_rn((float)p, 1.0f / 255.0f);
      float py = py_row;
#pragma unroll 1
      for (int s = 0; s < NSTEPS_; ++s) {
        float xc = fminf(fmaxf(px, 0.f), 1.f) * 2.0f;   // exact (*2)
        float yc = fminf(fmaxf(py, 0.f), 1.f) * 4.0f;   // exact (*4)
        float cxf = fminf(floorf(xc), 1.0f);
        float cyf = fminf(floorf(yc), 3.0f);
        float xr = xc - cxf, yr = yc - cyf;
        int tri = (yr <= xr) ? ((yr <= 1.0f - xr) ? 0 : 1)
                             : ((yr <= 1.0f - xr) ? 3 : 2);
        int cid = ((((int)cyf) << 1) + (int)cxf) * 4 + tri;
        float2 q0 = sA2[cid];        // {a00, a10}
        float2 q1 = sA2[32 + cid];   // {a01, a11}
        float2 q2 = sA2[64 + cid];   // {a02, a12}
        float vx = __fadd_rn(__fadd_rn(__fmul_rn(q0.x, px), __fmul_rn(q1.x, py)), q2.x);
        float vy = __fadd_rn(__fadd_rn(__fmul_rn(q0.y, px), __fmul_rn(q1.y, py)), q2.y);
        px = __fadd_rn(px, __fmul_rn(0.02f, vx));
        py = __fadd_rn(py, __fmul_rn(0.02f, vy));
      }
      float gx = __fmul_rn(fminf(fmaxf(px, 0.f), 1.f), 255.0f);
      float gy = __fmul_rn(fminf(fmaxf(py, 0.f), 1.f), 255.0f);
      int ix = min((int)gx, 254);   // gx >= 0 so (int) == floor
      int iy = min((int)gy, 254);
      float wx = __fadd_rn(gx, -(float)ix);
      float wy = __fadd_rn(gy, -(float)iy);
      sOff[p] = (iy << 8) + ix;
      float4 w4;
      w4.x = (1.f - wx) * (1.f - wy);
      w4.y = wx * (1.f - wy);
      w4.z = (1.f - wx) * wy;
      w4.w = wx * wy;
      sW[p] = w4;
      __hip_atomic_store(&sFlag, c + 1, __ATOMIC_RELEASE, __HIP_MEMORY_SCOPE_WORKGROUP);
    }
  }

  // ---- sampling: all waves; wave w owns groups g == w (mod 4), 16 each ----
#pragma unroll 1
  for (int k = 0; k < 16; k += 2) {
    int g0 = (k << 2) | wv;        // 0..63
    int g1 = g0 + 4;
    if (wv < 3) {
      int need = (g1 >> 4) + 1;    // chunk needed for the later group
      while (__hip_atomic_load(&sFlag, __ATOMIC_ACQUIRE, __HIP_MEMORY_SCOPE_WORKGROUP) < need)
        __builtin_amdgcn_s_sleep(2);
    }
    int p0 = (g0 << 2) + lp;
    int p1 = (g1 << 2) + lp;
    int off0 = sOff[p0];  float4 W0 = sW[p0];
    int off1 = sOff[p1];  float4 W1 = sW[p1];
    const float4* q0 = xb4 + ((size_t)off0 << 4) + lc;
    const float4* q1 = xb4 + ((size_t)off1 << 4) + lc;
    float4 A0 = q0[0];
    float4 A1 = q0[16];              // x0+1
    float4 A2 = q0[16 * 256];        // y0+1
    float4 A3 = q0[16 * 256 + 16];   // x0+1, y0+1
    float4 B0 = q1[0];
    float4 B1 = q1[16];
    float4 B2 = q1[16 * 256];
    float4 B3 = q1[16 * 256 + 16];
    vf4 o0, o1;
    o0.x = A0.x * W0.x + A1.x * W0.y + A2.x * W0.z + A3.x * W0.w;
    o0.y = A0.y * W0.x + A1.y * W0.y + A2.y * W0.z + A3.y * W0.w;
    o0.z = A0.z * W0.x + A1.z * W0.y + A2.z * W0.z + A3.z * W0.w;
    o0.w = A0.w * W0.x + A1.w * W0.y + A2.w * W0.z + A3.w * W0.w;
    o1.x = B0.x * W1.x + B1.x * W1.y + B2.x * W1.z + B3.x * W1.w;
    o1.y = B0.y * W1.x + B1.y * W1.y + B2.y * W1.z + B3.y * W1.w;
    o1.z = B0.z * W1.x + B1.z * W1.y + B2.z * W1.z + B3.z * W1.w;
    o1.w = B0.w * W1.x + B1.w * W1.y + B2.w * W1.z + B3.w * W1.w;
    __builtin_nontemporal_store(o0, (vf4*)(ob + (size_t)p0 * CC + (lc << 2)));
    __builtin_nontemporal_store(o1, (vf4*)(ob + (size_t)p1 * CC + (lc << 2)));
  }
}

extern "C" void kernel_launch(void* const* d_in, const int* in_sizes, int n_in,
                              void* d_out, int out_size, void* d_ws, size_t ws_size,
                              hipStream_t stream) {
  const float* x     = (const float*)d_in[0];   // (8,256,256,64) f32
  const float* theta = (const float*)d_in[1];   // (8,22) f32
  float* out  = (float*)d_out;                  // (8,256,256,64) f32
  float* Abuf = (float*)d_ws;                   // 8*192 floats = 6 KiB

  cpab_build_A<<<1, 256, 0, stream>>>(theta, Abuf);
  cpab_pc<<<NBATCH * HWPTS / 256, 256, 0, stream>>>(x, Abuf, out);
}

// Round 9
// 44.624 us; speedup vs baseline: 1.1468x; 1.1313x over previous
//
#include <hip/hip_runtime.h>

#define NBATCH 8
#define HH 256
#define WW 256
#define CC 64
#define HWPTS 65536   // HH*WW
#define NSTEPS_ 50

typedef float vf4 __attribute__((ext_vector_type(4)));

// ---------------------------------------------------------------------------
// Kernel 1: build per-(b,t) affine matrices A (2x3) from theta, PRE-SCALED to
// cell units (X=2*px, Y=4*py):  vx' = 2*vx = a0*X + (a1/2)*Y + 2*a2
//                               vy' = 4*vy = 2*a3*X + a4*Y + 4*a5
// (power-of-2 scalings are exact). Layout float2-packed, transposed:
//   q0={a0,2a3} at [cid], q1={a1/2,a4} at [32+cid], q2={2a2,4a5} at [64+cid]
// ---------------------------------------------------------------------------
__global__ __launch_bounds__(256) void cpab_build_A(const float* __restrict__ theta,
                                                    float* __restrict__ Aout) {
  int tid = threadIdx.x;           // 0..255 == b*32 + t
  int b = tid >> 5, t = tid & 31;
  int cell = t >> 2, k = t & 3;
  int ci = cell & 1, cj = cell >> 1;
  int ll = cj * 3 + ci;
  int lr = ll + 1, ul = ll + 3, ur = ll + 4;
  int cen = 15 + cj * 2 + ci;
  int v0, v1, v2 = cen;
  if (k == 0)      { v0 = ll; v1 = lr; }
  else if (k == 1) { v0 = lr; v1 = ur; }
  else if (k == 2) { v0 = ur; v1 = ul; }
  else             { v0 = ul; v1 = ll; }

  int vs[3] = {v0, v1, v2};
  double xs[3], ys[3];
  float Vx[3], Vy[3];
  for (int q = 0; q < 3; ++q) {
    int v = vs[q];
    if (v < 15) { xs[q] = (double)(v % 3) * 0.5; ys[q] = (double)(v / 3) * 0.25; }
    else { int u = v - 15; xs[q] = ((double)(u & 1) + 0.5) * 0.5;
           ys[q] = ((double)(u >> 1) + 0.5) * 0.25; }
    int s = (v == 4) ? 0 : (v == 7) ? 1 : (v == 10) ? 2 : (v >= 15) ? (v - 12) : -1;
    if (s >= 0) { Vx[q] = theta[b * 22 + 2 * s]; Vy[q] = theta[b * 22 + 2 * s + 1]; }
    else        { Vx[q] = 0.f; Vy[q] = 0.f; }
  }
  double x0 = xs[0], x1 = xs[1], x2 = xs[2];
  double y0 = ys[0], y1 = ys[1], y2 = ys[2];
  double det = x0 * (y1 - y2) - x1 * (y0 - y2) + x2 * (y0 - y1);
  // P = [[x0,x1,x2],[y0,y1,y2],[1,1,1]];  inv = adj^T / det
  double inv[3][3] = {
      {y1 - y2, x2 - x1, x1 * y2 - x2 * y1},
      {y2 - y0, x0 - x2, x2 * y0 - x0 * y2},
      {y0 - y1, x1 - x0, x0 * y1 - x1 * y0}};
  // scale factors for cell-unit state: col w=0 (x-coeff): ax*1, ay*2
  //                                    col w=1 (y-coeff): ax*0.5, ay*1
  //                                    col w=2 (const)  : ax*2, ay*4
  const float sxw[3] = {1.0f, 0.5f, 2.0f};
  const float syw[3] = {2.0f, 1.0f, 4.0f};
  for (int w = 0; w < 3; ++w) {
    float i0 = (float)(inv[0][w] / det);
    float i1 = (float)(inv[1][w] / det);
    float i2 = (float)(inv[2][w] / det);
    float ax = __fadd_rn(__fadd_rn(__fmul_rn(Vx[0], i0), __fmul_rn(Vx[1], i1)),
                         __fmul_rn(Vx[2], i2));
    float ay = __fadd_rn(__fadd_rn(__fmul_rn(Vy[0], i0), __fmul_rn(Vy[1], i1)),
                         __fmul_rn(Vy[2], i2));
    Aout[b * 192 + (w * 32 + t) * 2]     = ax * sxw[w];   // exact pow2 scale
    Aout[b * 192 + (w * 32 + t) * 2 + 1] = ay * syw[w];   // exact pow2 scale
  }
}

// ---------------------------------------------------------------------------
// Kernel 2: R5 structure verbatim in the memory phase; integration runs in
// cell units (X,Y) with med3 clamps and FMA (velocity + update).
// ---------------------------------------------------------------------------
__global__ __launch_bounds__(256) void cpab_warp_sample(const float* __restrict__ xin,
                                                        const float* __restrict__ Ain,
                                                        float* __restrict__ out) {
  __shared__ float2 sA2[96];
  __shared__ int    sOff[256];
  __shared__ float4 sW[256];

  int tid = threadIdx.x;
  int bid = blockIdx.x;
  int swz = ((bid & 7) << 8) | (bid >> 3);   // bijective: 2048 = 8 * 256
  int base_pt = swz << 8;                    // 256 points per block
  int b = bid & 7;                           // batch == XCD

  if (tid < 192) ((float*)sA2)[tid] = Ain[b * 192 + tid];
  __syncthreads();

  {
    int hw = (base_pt + tid) & (HWPTS - 1);
    int w = hw & 255, h = hw >> 8;
    // np.linspace(0,1,256): i * (1/255) with exact endpoint; X=2px,Y=4py exact
    float px = (w == 255) ? 1.0f : __fmul_rn((float)w, 1.0f / 255.0f);
    float py = (h == 255) ? 1.0f : __fmul_rn((float)h, 1.0f / 255.0f);
    float X = px * 2.0f;    // exact
    float Y = py * 4.0f;    // exact
#pragma unroll 1
    for (int s = 0; s < NSTEPS_; ++s) {
      float xc = __builtin_amdgcn_fmed3f(X, 0.0f, 2.0f);  // == clip(px,0,1)*2
      float yc = __builtin_amdgcn_fmed3f(Y, 0.0f, 4.0f);  // == clip(py,0,1)*4
      float cxf = fminf(floorf(xc), 1.0f);
      float cyf = fminf(floorf(yc), 3.0f);
      float xr = xc - cxf, yr = yc - cyf;
      int tri = (yr <= xr) ? ((yr <= 1.0f - xr) ? 0 : 1)
                           : ((yr <= 1.0f - xr) ? 3 : 2);
      int cid = ((((int)cyf) << 1) + (int)cxf) * 4 + tri;
      float2 q0 = sA2[cid];        // {a0, 2a3}
      float2 q1 = sA2[32 + cid];   // {a1/2, a4}
      float2 q2 = sA2[64 + cid];   // {2a2, 4a5}
      float vx = __builtin_fmaf(q0.x, X, __builtin_fmaf(q1.x, Y, q2.x));
      float vy = __builtin_fmaf(q0.y, X, __builtin_fmaf(q1.y, Y, q2.y));
      X = __builtin_fmaf(0.02f, vx, X);
      Y = __builtin_fmaf(0.02f, vy, Y);
    }
    // gx = clip(px,0,1)*255 = med3(X,0,2)*127.5 ; gy = med3(Y,0,4)*63.75
    float gx = __fmul_rn(__builtin_amdgcn_fmed3f(X, 0.0f, 2.0f), 127.5f);
    float gy = __fmul_rn(__builtin_amdgcn_fmed3f(Y, 0.0f, 4.0f), 63.75f);
    int ix = min((int)gx, 254);   // gx >= 0 so (int) == floor
    int iy = min((int)gy, 254);
    float wx = __fadd_rn(gx, -(float)ix);
    float wy = __fadd_rn(gy, -(float)iy);
    sOff[tid] = (iy << 8) + ix;
    float4 w4;
    w4.x = (1.f - wx) * (1.f - wy);
    w4.y = wx * (1.f - wy);
    w4.z = (1.f - wx) * wy;
    w4.w = wx * wy;
    sW[tid] = w4;
  }
  __syncthreads();

  const float4* xb4 = (const float4*)(xin + (size_t)b * ((size_t)HWPTS * CC));
  float* ob = out + (size_t)base_pt * CC;
  int lane_c = tid & 15;     // channel chunk 0..15
  int lane_p = tid >> 4;     // point sub-index 0..15

#pragma unroll
  for (int r = 0; r < 4; ++r) {
    float4 L[4][4];
    float4 W[4];
    const float4* q[4];
#pragma unroll
    for (int g = 0; g < 4; ++g) {
      int p = r * 16 + lane_p + g * 64;
      int off = sOff[p];
      W[g] = sW[p];
      q[g] = xb4 + ((size_t)off << 4) + lane_c;
    }
#pragma unroll
    for (int g = 0; g < 4; ++g) {
      L[g][0] = q[g][0];
      L[g][1] = q[g][16];              // x0+1
      L[g][2] = q[g][16 * 256];        // y0+1
      L[g][3] = q[g][16 * 256 + 16];   // x0+1, y0+1
    }
#pragma unroll
    for (int g = 0; g < 4; ++g) {
      int p = r * 16 + lane_p + g * 64;
      vf4 o;
      o.x = L[g][0].x * W[g].x + L[g][1].x * W[g].y + L[g][2].x * W[g].z + L[g][3].x * W[g].w;
      o.y = L[g][0].y * W[g].x + L[g][1].y * W[g].y + L[g][2].y * W[g].z + L[g][3].y * W[g].w;
      o.z = L[g][0].z * W[g].x + L[g][1].z * W[g].y + L[g][2].z * W[g].z + L[g][3].z * W[g].w;
      o.w = L[g][0].w * W[g].x + L[g][1].w * W[g].y + L[g][2].w * W[g].z + L[g][3].w * W[g].w;
      __builtin_nontemporal_store(o, (vf4*)(ob + (size_t)p * CC + (lane_c << 2)));
    }
  }
}

extern "C" void kernel_launch(void* const* d_in, const int* in_sizes, int n_in,
                              void* d_out, int out_size, void* d_ws, size_t ws_size,
                              hipStream_t stream) {
  const float* x     = (const float*)d_in[0];   // (8,256,256,64) f32
  const float* theta = (const float*)d_in[1];   // (8,22) f32
  float* out  = (float*)d_out;                  // (8,256,256,64) f32
  float* Abuf = (float*)d_ws;                   // 8*192 floats = 6 KiB

  cpab_build_A<<<1, 256, 0, stream>>>(theta, Abuf);
  cpab_warp_sample<<<NBATCH * HWPTS / 256, 256, 0, stream>>>(x, Abuf, out);
}

// Round 10
// 41.304 us; speedup vs baseline: 1.2389x; 1.0804x over previous
//
#include <hip/hip_runtime.h>

#define NBATCH 8
#define HH 256
#define WW 256
#define CC 64
#define HWPTS 65536   // HH*WW
#define NSTEPS_ 50

typedef float vf4 __attribute__((ext_vector_type(4)));

// ---------------------------------------------------------------------------
// Single fused kernel. 2048 blocks x 256 thr; block = (batch=bid&7 -> XCD,
// row=bid>>3).
// Step 0: threads 0..31 build this batch's 24 affine matrices A (2x3) from
//   theta directly into LDS (f64 inverse, f32 einsum — op-identical to the
//   old kernel 1). No separate dispatch, no global Abuf round-trip.
// Phase 1: each thread integrates its point (A float2-packed in LDS,
//   3x ds_read_b64/step); offsets + bilinear weights published to LDS.
// Phase 2: 4 iterations x 4-point groups: 16 float4 gathers issued
//   back-to-back, then 4 blends + nontemporal stores.
// Cross-block overlap (8 block-generations/CU) hides phase-1 VALU under
// other blocks' phase-2 memory; intra-block structures that tried to force
// this explicitly (R4/R6/R7/R8) all lost to occupancy/latency costs.
// ---------------------------------------------------------------------------
__global__ __launch_bounds__(256) void cpab_fused(const float* __restrict__ xin,
                                                  const float* __restrict__ theta,
                                                  float* __restrict__ out) {
  __shared__ float2 sA2[96];
  __shared__ int    sOff[256];
  __shared__ float4 sW[256];

  int tid = threadIdx.x;
  int bid = blockIdx.x;
  int swz = ((bid & 7) << 8) | (bid >> 3);   // bijective: 2048 = 8 * 256
  int base_pt = swz << 8;                    // 256 points per block
  int b = bid & 7;                           // batch == XCD

  // ---- step 0: build A for batch b (threads 0..31, one per triangle) ----
  if (tid < 32) {
    int t = tid;
    int cell = t >> 2, k = t & 3;
    int ci = cell & 1, cj = cell >> 1;
    int ll = cj * 3 + ci;
    int lr = ll + 1, ul = ll + 3, ur = ll + 4;
    int cen = 15 + cj * 2 + ci;
    int v0, v1, v2 = cen;
    if (k == 0)      { v0 = ll; v1 = lr; }
    else if (k == 1) { v0 = lr; v1 = ur; }
    else if (k == 2) { v0 = ur; v1 = ul; }
    else             { v0 = ul; v1 = ll; }

    int vs[3] = {v0, v1, v2};
    double xs[3], ys[3];
    float Vx[3], Vy[3];
    for (int q = 0; q < 3; ++q) {
      int v = vs[q];
      if (v < 15) { xs[q] = (double)(v % 3) * 0.5; ys[q] = (double)(v / 3) * 0.25; }
      else { int u = v - 15; xs[q] = ((double)(u & 1) + 0.5) * 0.5;
             ys[q] = ((double)(u >> 1) + 0.5) * 0.25; }
      int s = (v == 4) ? 0 : (v == 7) ? 1 : (v == 10) ? 2 : (v >= 15) ? (v - 12) : -1;
      if (s >= 0) { Vx[q] = theta[b * 22 + 2 * s]; Vy[q] = theta[b * 22 + 2 * s + 1]; }
      else        { Vx[q] = 0.f; Vy[q] = 0.f; }
    }
    double x0 = xs[0], x1 = xs[1], x2 = xs[2];
    double y0 = ys[0], y1 = ys[1], y2 = ys[2];
    double det = x0 * (y1 - y2) - x1 * (y0 - y2) + x2 * (y0 - y1);
    // P = [[x0,x1,x2],[y0,y1,y2],[1,1,1]];  inv = adj^T / det
    double inv[3][3] = {
        {y1 - y2, x2 - x1, x1 * y2 - x2 * y1},
        {y2 - y0, x0 - x2, x2 * y0 - x0 * y2},
        {y0 - y1, x1 - x0, x0 * y1 - x1 * y0}};
    for (int w = 0; w < 3; ++w) {
      float i0 = (float)(inv[0][w] / det);
      float i1 = (float)(inv[1][w] / det);
      float i2 = (float)(inv[2][w] / det);
      float ax = __fadd_rn(__fadd_rn(__fmul_rn(Vx[0], i0), __fmul_rn(Vx[1], i1)),
                           __fmul_rn(Vx[2], i2));
      float ay = __fadd_rn(__fadd_rn(__fmul_rn(Vy[0], i0), __fmul_rn(Vy[1], i1)),
                           __fmul_rn(Vy[2], i2));
      ((float*)sA2)[(w * 32 + t) * 2]     = ax;
      ((float*)sA2)[(w * 32 + t) * 2 + 1] = ay;
    }
  }
  __syncthreads();

  // ---- phase 1: integrate own point ----
  {
    int hw = (base_pt + tid) & (HWPTS - 1);
    int w = hw & 255, h = hw >> 8;
    // np.linspace(0,1,256): i * (1/255) with exact endpoint
    float px = (w == 255) ? 1.0f : __fmul_rn((float)w, 1.0f / 255.0f);
    float py = (h == 255) ? 1.0f : __fmul_rn((float)h, 1.0f / 255.0f);
#pragma unroll 1
    for (int s = 0; s < NSTEPS_; ++s) {
      float xc = fminf(fmaxf(px, 0.f), 1.f) * 2.0f;   // exact (*2)
      float yc = fminf(fmaxf(py, 0.f), 1.f) * 4.0f;   // exact (*4)
      float cxf = fminf(floorf(xc), 1.0f);
      float cyf = fminf(floorf(yc), 3.0f);
      float xr = xc - cxf, yr = yc - cyf;
      int tri = (yr <= xr) ? ((yr <= 1.0f - xr) ? 0 : 1)
                           : ((yr <= 1.0f - xr) ? 3 : 2);
      int cid = ((((int)cyf) << 1) + (int)cxf) * 4 + tri;
      float2 q0 = sA2[cid];        // {a00, a10}
      float2 q1 = sA2[32 + cid];   // {a01, a11}
      float2 q2 = sA2[64 + cid];   // {a02, a12}
      float vx = __fadd_rn(__fadd_rn(__fmul_rn(q0.x, px), __fmul_rn(q1.x, py)), q2.x);
      float vy = __fadd_rn(__fadd_rn(__fmul_rn(q0.y, px), __fmul_rn(q1.y, py)), q2.y);
      px = __fadd_rn(px, __fmul_rn(0.02f, vx));
      py = __fadd_rn(py, __fmul_rn(0.02f, vy));
    }
    float gx = __fmul_rn(fminf(fmaxf(px, 0.f), 1.f), 255.0f);
    float gy = __fmul_rn(fminf(fmaxf(py, 0.f), 1.f), 255.0f);
    int ix = min((int)gx, 254);   // gx >= 0 so (int) == floor
    int iy = min((int)gy, 254);
    float wx = __fadd_rn(gx, -(float)ix);
    float wy = __fadd_rn(gy, -(float)iy);
    sOff[tid] = (iy << 8) + ix;
    float4 w4;
    w4.x = (1.f - wx) * (1.f - wy);
    w4.y = wx * (1.f - wy);
    w4.z = (1.f - wx) * wy;
    w4.w = wx * wy;
    sW[tid] = w4;
  }
  __syncthreads();

  // ---- phase 2: gather + blend + store ----
  const float4* xb4 = (const float4*)(xin + (size_t)b * ((size_t)HWPTS * CC));
  float* ob = out + (size_t)base_pt * CC;
  int lane_c = tid & 15;     // channel chunk 0..15
  int lane_p = tid >> 4;     // point sub-index 0..15

#pragma unroll
  for (int r = 0; r < 4; ++r) {
    float4 L[4][4];
    float4 W[4];
    const float4* q[4];
#pragma unroll
    for (int g = 0; g < 4; ++g) {
      int p = r * 16 + lane_p + g * 64;
      int off = sOff[p];
      W[g] = sW[p];
      q[g] = xb4 + ((size_t)off << 4) + lane_c;
    }
#pragma unroll
    for (int g = 0; g < 4; ++g) {
      L[g][0] = q[g][0];
      L[g][1] = q[g][16];              // x0+1
      L[g][2] = q[g][16 * 256];        // y0+1
      L[g][3] = q[g][16 * 256 + 16];   // x0+1, y0+1
    }
#pragma unroll
    for (int g = 0; g < 4; ++g) {
      int p = r * 16 + lane_p + g * 64;
      vf4 o;
      o.x = L[g][0].x * W[g].x + L[g][1].x * W[g].y + L[g][2].x * W[g].z + L[g][3].x * W[g].w;
      o.y = L[g][0].y * W[g].x + L[g][1].y * W[g].y + L[g][2].y * W[g].z + L[g][3].y * W[g].w;
      o.z = L[g][0].z * W[g].x + L[g][1].z * W[g].y + L[g][2].z * W[g].z + L[g][3].z * W[g].w;
      o.w = L[g][0].w * W[g].x + L[g][1].w * W[g].y + L[g][2].w * W[g].z + L[g][3].w * W[g].w;
      __builtin_nontemporal_store(o, (vf4*)(ob + (size_t)p * CC + (lane_c << 2)));
    }
  }
}

extern "C" void kernel_launch(void* const* d_in, const int* in_sizes, int n_in,
                              void* d_out, int out_size, void* d_ws, size_t ws_size,
                              hipStream_t stream) {
  const float* x     = (const float*)d_in[0];   // (8,256,256,64) f32
  const float* theta = (const float*)d_in[1];   // (8,22) f32
  float* out  = (float*)d_out;                  // (8,256,256,64) f32

  cpab_fused<<<NBATCH * HWPTS / 256, 256, 0, stream>>>(x, theta, out);
}